// Round 1
// 470.564 us; speedup vs baseline: 1.0147x; 1.0147x over previous
//
#include <hip/hip_runtime.h>
#include <hip/hip_bf16.h>

// Problem constants: B=1, L=4, C=128, H=240, W=480, LMAX=6, R=8
#define L_DIM 4
#define C_DIM 128
#define CH_DIM 64          // C/2
#define HW 115200          // 240*480
#define HW4 28800          // HW/4
#define R_DIM 8
#define K_DIM 36           // LMAX^2
#define WF_DIM 1312        // C*R + R*K = 1024 + 288
#define WF_TOT 5248        // L * WF_DIM
#define PBLK 225           // HW / 512 (512 pixels per block, 2 per thread)

typedef __attribute__((ext_vector_type(16))) float vf16;
typedef __attribute__((ext_vector_type(4)))  float vf4;
typedef __attribute__((ext_vector_type(2)))  float vf2;

// ---------------------------------------------------------------------------
// K1: ctx[l,c] = mean over HW of x[l,c,:,:]. One block per (l,c): 512 blocks.
// 4-deep load ILP to keep ~32KB/CU in flight (Little's law for ~900cy HBM lat).
// Normal (caching) loads on purpose: this pass warms L3 with x for K3's re-read.
// ---------------------------------------------------------------------------
__global__ __launch_bounds__(256) void mean_pool_kernel(
    const float* __restrict__ x, float* __restrict__ ctx) {
  const int b = blockIdx.x;  // l*128 + c
  const float4* xb = (const float4*)(x + (size_t)b * HW);
  float s0 = 0.f, s1 = 0.f, s2 = 0.f, s3 = 0.f;
  int i = threadIdx.x;
  #pragma unroll 1
  for (; i + 768 < HW4; i += 1024) {
    float4 a = xb[i];
    float4 bq = xb[i + 256];
    float4 c = xb[i + 512];
    float4 d = xb[i + 768];
    s0 += (a.x + a.y) + (a.z + a.w);
    s1 += (bq.x + bq.y) + (bq.z + bq.w);
    s2 += (c.x + c.y) + (c.z + c.w);
    s3 += (d.x + d.y) + (d.z + d.w);
  }
  for (; i < HW4; i += 256) {
    float4 a = xb[i];
    s0 += (a.x + a.y) + (a.z + a.w);
  }
  float s = (s0 + s1) + (s2 + s3);
  #pragma unroll
  for (int off = 32; off > 0; off >>= 1) s += __shfl_down(s, off, 64);
  __shared__ float wsum[4];
  if ((threadIdx.x & 63) == 0) wsum[threadIdx.x >> 6] = s;
  __syncthreads();
  if (threadIdx.x == 0) {
    float t = (wsum[0] + wsum[1]) + (wsum[2] + wsum[3]);
    ctx[b] = t * (1.0f / (float)HW);
  }
}

// ---------------------------------------------------------------------------
// K2: hypernet. 21 blocks x 256 threads. Each block recomputes h (cheap, L2-hit
// Wa), then computes a 256-output slice of wf = h@Wb + bb. gain is folded into
// the W1 portion (oo < 1024): wf[l, c*8+r] *= gain[c].
// ---------------------------------------------------------------------------
__global__ __launch_bounds__(256) void hyper_kernel(
    const float* __restrict__ ctx, const float* __restrict__ Wa,
    const float* __restrict__ ba, const float* __restrict__ Wb,
    const float* __restrict__ bb, const float* __restrict__ gain,
    float* __restrict__ wf) {
  __shared__ float sctx[L_DIM * C_DIM];  // 512
  __shared__ float sh[L_DIM * CH_DIM];   // 256
  const int tid = threadIdx.x;
  sctx[tid] = ctx[tid];
  sctx[tid + 256] = ctx[tid + 256];
  __syncthreads();
  {
    const int l = tid >> 6, j = tid & 63;
    float acc = ba[j];
    #pragma unroll 16
    for (int c = 0; c < C_DIM; ++c) acc += sctx[l * C_DIM + c] * Wa[c * CH_DIM + j];
    sh[tid] = acc / (1.0f + __expf(-acc));  // silu
  }
  __syncthreads();
  const int o = blockIdx.x * 256 + tid;
  if (o < WF_TOT) {
    const int l = o / WF_DIM;
    const int oo = o - l * WF_DIM;
    float acc = bb[oo];
    #pragma unroll 16
    for (int j = 0; j < CH_DIM; ++j) acc += sh[l * CH_DIM + j] * Wb[j * WF_DIM + oo];
    if (oo < C_DIM * R_DIM) acc *= gain[oo >> 3];
    wf[o] = acc;
  }
}

// ---------------------------------------------------------------------------
// Kz: z[l,r,p] = sum_k W2[l,r,k] * Y[k,p].  Computed ONCE (previously this was
// recomputed in every one of 1800 bias blocks = 8x redundant Y stream + 8x FMA).
// 225 blocks x 256 threads, 2 px/thread. Traffic: 16.6 MB in + 14.7 MB out.
// Accumulation order (k ascending, single accumulator) identical to the old
// in-prologue computation -> bit-identical results.
// ---------------------------------------------------------------------------
__global__ __launch_bounds__(256) void zmap_kernel(
    const float* __restrict__ Y, const float* __restrict__ wf,
    float* __restrict__ z) {
  const int p = blockIdx.x * 512 + threadIdx.x * 2;
  float2 y[K_DIM];
  #pragma unroll
  for (int k = 0; k < K_DIM; ++k) y[k] = *(const float2*)(Y + k * HW + p);
  #pragma unroll 1
  for (int l = 0; l < L_DIM; ++l) {
    const float* w2base = wf + l * WF_DIM + C_DIM * R_DIM;
    #pragma unroll 1
    for (int r = 0; r < R_DIM; ++r) {
      vf16 a, bq; vf4 cq;
      const float* wp = w2base + r * K_DIM;
      asm volatile(
          "s_load_dwordx16 %0, %3, 0x0\n\t"
          "s_load_dwordx16 %1, %3, 0x40\n\t"
          "s_load_dwordx4  %2, %3, 0x80\n\t"
          "s_waitcnt lgkmcnt(0)"
          : "=&s"(a), "=&s"(bq), "=&s"(cq)
          : "s"(wp));
      float za = 0.f, zb = 0.f;
      #pragma unroll
      for (int k = 0; k < 16; ++k) { za += a[k] * y[k].x;      zb += a[k] * y[k].y; }
      #pragma unroll
      for (int k = 0; k < 16; ++k) { za += bq[k] * y[16 + k].x; zb += bq[k] * y[16 + k].y; }
      #pragma unroll
      for (int k = 0; k < 4; ++k)  { za += cq[k] * y[32 + k].x; zb += cq[k] * y[32 + k].y; }
      vf2 zv; zv.x = za; zv.y = zb;
      *(vf2*)(z + (size_t)(l * R_DIM + r) * HW + p) = zv;
    }
  }
}

// ---------------------------------------------------------------------------
// K3: out[l,c,p] = x[l,c,p] + sum_r gW1[l,c,r] * z[l,r,p]
// Now a pure streaming kernel: prologue is 8 coalesced float2 loads of z
// (previously: 36 Y float2 loads pinning 72 VGPRs + 8 serialized s_load fences
// + 576 FMA, per block). gW1 rows still via s_load -> SGPR FMA operands.
// out stores are nontemporal so the write stream doesn't evict x from L3
// (x = 236 MB < 256 MB Infinity Cache, warmed by K1).
// Grid: L * PBLK * 2 channel-halves = 1800 blocks.
// ---------------------------------------------------------------------------
__global__ __launch_bounds__(256) void bias_add_kernel(
    const float* __restrict__ x, const float* __restrict__ z,
    const float* __restrict__ wf, float* __restrict__ out) {
  const int b = blockIdx.x;
  const int half = b & 1;
  const int t = b >> 1;          // [0, 900)
  const int l = t / PBLK;
  const int pb = t - l * PBLK;
  const int p = pb * 512 + threadIdx.x * 2;

  // ---- prologue: z[r] for both pixels (precomputed by zmap_kernel) ----
  float z0[R_DIM], z1[R_DIM];
  {
    const float* zp = z + (size_t)l * R_DIM * HW + p;
    #pragma unroll
    for (int r = 0; r < R_DIM; ++r) {
      float2 zv = *(const float2*)(zp + r * HW);
      z0[r] = zv.x; z1[r] = zv.y;
    }
  }

  // ---- main loop: 64 channels, 8 at a time (gW1 rows via one s_load group) ----
  const float* w1base = wf + l * WF_DIM + half * (64 * R_DIM);
  const size_t xoff = (size_t)l * C_DIM * HW + (size_t)half * 64 * HW + (size_t)p;
  const float* xp = x + xoff;
  float* op = out + xoff;

  #pragma unroll 1
  for (int cc = 0; cc < 64; cc += 8) {
    vf16 w0, w1, w2, w3;  // 64 floats = gW1 rows for channels cc..cc+7
    const float* wp = w1base + cc * R_DIM;
    asm volatile(
        "s_load_dwordx16 %0, %4, 0x0\n\t"
        "s_load_dwordx16 %1, %4, 0x40\n\t"
        "s_load_dwordx16 %2, %4, 0x80\n\t"
        "s_load_dwordx16 %3, %4, 0xC0\n\t"
        "s_waitcnt lgkmcnt(0)"
        : "=&s"(w0), "=&s"(w1), "=&s"(w2), "=&s"(w3)
        : "s"(wp));
    float wl[64];
    #pragma unroll
    for (int k = 0; k < 16; ++k) {
      wl[k] = w0[k]; wl[16 + k] = w1[k]; wl[32 + k] = w2[k]; wl[48 + k] = w3[k];
    }
    #pragma unroll
    for (int c8 = 0; c8 < 8; ++c8) {
      float a0 = 0.f, a1 = 0.f;
      #pragma unroll
      for (int r = 0; r < R_DIM; ++r) {
        const float wv = wl[c8 * 8 + r];
        a0 += wv * z0[r];
        a1 += wv * z1[r];
      }
      const size_t co = (size_t)(cc + c8) * HW;
      float2 xv = *(const float2*)(xp + co);
      vf2 ov;
      ov.x = xv.x + a0;
      ov.y = xv.y + a1;
      __builtin_nontemporal_store(ov, (vf2*)(op + co));
    }
  }
}

// ---------------------------------------------------------------------------
extern "C" void kernel_launch(void* const* d_in, const int* in_sizes, int n_in,
                              void* d_out, int out_size, void* d_ws, size_t ws_size,
                              hipStream_t stream) {
  const float* x    = (const float*)d_in[0];
  const float* Wa   = (const float*)d_in[1];
  const float* ba   = (const float*)d_in[2];
  const float* Wb   = (const float*)d_in[3];
  const float* bb   = (const float*)d_in[4];
  const float* gain = (const float*)d_in[5];
  const float* Y    = (const float*)d_in[6];
  float* out = (float*)d_out;

  float* ctx = (float*)d_ws;                    // 512 floats
  float* wf  = (float*)((char*)d_ws + 4096);    // 5248 floats
  float* z   = (float*)((char*)d_ws + 32768);   // 4*8*115200 floats = 14.7 MB

  mean_pool_kernel<<<L_DIM * C_DIM, 256, 0, stream>>>(x, ctx);
  hyper_kernel<<<21, 256, 0, stream>>>(ctx, Wa, ba, Wb, bb, gain, wf);
  zmap_kernel<<<PBLK, 256, 0, stream>>>(Y, wf, z);
  bias_add_kernel<<<L_DIM * PBLK * 2, 256, 0, stream>>>(x, z, wf, out);
}

// Round 2
// 468.549 us; speedup vs baseline: 1.0190x; 1.0043x over previous
//
#include <hip/hip_runtime.h>
#include <hip/hip_bf16.h>

// Problem constants: B=1, L=4, C=128, H=240, W=480, LMAX=6, R=8
#define L_DIM 4
#define C_DIM 128
#define CH_DIM 64          // C/2
#define HW 115200          // 240*480
#define HW4 28800          // HW/4
#define R_DIM 8
#define K_DIM 36           // LMAX^2
#define WF_DIM 1312        // C*R + R*K = 1024 + 288
#define WF_TOT 5248        // L * WF_DIM
#define PBLK 225           // HW / 512 (Kz: 512 px per block, 2 per thread)
#define PBLK4 113          // ceil(HW/1024) (K3: 1024 px per block, 4 per thread)

typedef __attribute__((ext_vector_type(16))) float vf16;
typedef __attribute__((ext_vector_type(4)))  float vf4;
typedef __attribute__((ext_vector_type(2)))  float vf2;

// ---------------------------------------------------------------------------
// K1: ctx[l,c] = mean over HW of x[l,c,:,:]. One block per (l,c): 512 blocks.
// 4-deep load ILP (~32KB/CU in flight vs ~9.3KB needed at 900cy HBM latency).
// Normal (caching) loads on purpose: this pass warms L3 with x for K3's re-read.
// ---------------------------------------------------------------------------
__global__ __launch_bounds__(256) void mean_pool_kernel(
    const float* __restrict__ x, float* __restrict__ ctx) {
  const int b = blockIdx.x;  // l*128 + c
  const float4* xb = (const float4*)(x + (size_t)b * HW);
  float s0 = 0.f, s1 = 0.f, s2 = 0.f, s3 = 0.f;
  int i = threadIdx.x;
  #pragma unroll 1
  for (; i + 768 < HW4; i += 1024) {
    float4 a = xb[i];
    float4 bq = xb[i + 256];
    float4 c = xb[i + 512];
    float4 d = xb[i + 768];
    s0 += (a.x + a.y) + (a.z + a.w);
    s1 += (bq.x + bq.y) + (bq.z + bq.w);
    s2 += (c.x + c.y) + (c.z + c.w);
    s3 += (d.x + d.y) + (d.z + d.w);
  }
  for (; i < HW4; i += 256) {
    float4 a = xb[i];
    s0 += (a.x + a.y) + (a.z + a.w);
  }
  float s = (s0 + s1) + (s2 + s3);
  #pragma unroll
  for (int off = 32; off > 0; off >>= 1) s += __shfl_down(s, off, 64);
  __shared__ float wsum[4];
  if ((threadIdx.x & 63) == 0) wsum[threadIdx.x >> 6] = s;
  __syncthreads();
  if (threadIdx.x == 0) {
    float t = (wsum[0] + wsum[1]) + (wsum[2] + wsum[3]);
    ctx[b] = t * (1.0f / (float)HW);
  }
}

// ---------------------------------------------------------------------------
// K2: hypernet. 21 blocks x 256 threads. Each block recomputes h (cheap, L2-hit
// Wa), then computes a 256-output slice of wf = h@Wb + bb. gain is folded into
// the W1 portion (oo < 1024): wf[l, c*8+r] *= gain[c].
// ---------------------------------------------------------------------------
__global__ __launch_bounds__(256) void hyper_kernel(
    const float* __restrict__ ctx, const float* __restrict__ Wa,
    const float* __restrict__ ba, const float* __restrict__ Wb,
    const float* __restrict__ bb, const float* __restrict__ gain,
    float* __restrict__ wf) {
  __shared__ float sctx[L_DIM * C_DIM];  // 512
  __shared__ float sh[L_DIM * CH_DIM];   // 256
  const int tid = threadIdx.x;
  sctx[tid] = ctx[tid];
  sctx[tid + 256] = ctx[tid + 256];
  __syncthreads();
  {
    const int l = tid >> 6, j = tid & 63;
    float acc = ba[j];
    #pragma unroll 16
    for (int c = 0; c < C_DIM; ++c) acc += sctx[l * C_DIM + c] * Wa[c * CH_DIM + j];
    sh[tid] = acc / (1.0f + __expf(-acc));  // silu
  }
  __syncthreads();
  const int o = blockIdx.x * 256 + tid;
  if (o < WF_TOT) {
    const int l = o / WF_DIM;
    const int oo = o - l * WF_DIM;
    float acc = bb[oo];
    #pragma unroll 16
    for (int j = 0; j < CH_DIM; ++j) acc += sh[l * CH_DIM + j] * Wb[j * WF_DIM + oo];
    if (oo < C_DIM * R_DIM) acc *= gain[oo >> 3];
    wf[o] = acc;
  }
}

// ---------------------------------------------------------------------------
// Kz: z[l,r,p] = sum_k W2[l,r,k] * Y[k,p].  Computed ONCE.
// 225 blocks x 256 threads, 2 px/thread. Traffic: 16.6 MB in + 14.7 MB out.
// Normal stores: z stays L3-resident for K3's immediate consumption.
// Accumulation order (k ascending, single accumulator) -> bit-identical.
// ---------------------------------------------------------------------------
__global__ __launch_bounds__(256) void zmap_kernel(
    const float* __restrict__ Y, const float* __restrict__ wf,
    float* __restrict__ z) {
  const int p = blockIdx.x * 512 + threadIdx.x * 2;
  float2 y[K_DIM];
  #pragma unroll
  for (int k = 0; k < K_DIM; ++k) y[k] = *(const float2*)(Y + k * HW + p);
  #pragma unroll 1
  for (int l = 0; l < L_DIM; ++l) {
    const float* w2base = wf + l * WF_DIM + C_DIM * R_DIM;
    #pragma unroll 1
    for (int r = 0; r < R_DIM; ++r) {
      vf16 a, bq; vf4 cq;
      const float* wp = w2base + r * K_DIM;
      asm volatile(
          "s_load_dwordx16 %0, %3, 0x0\n\t"
          "s_load_dwordx16 %1, %3, 0x40\n\t"
          "s_load_dwordx4  %2, %3, 0x80\n\t"
          "s_waitcnt lgkmcnt(0)"
          : "=&s"(a), "=&s"(bq), "=&s"(cq)
          : "s"(wp));
      float za = 0.f, zb = 0.f;
      #pragma unroll
      for (int k = 0; k < 16; ++k) { za += a[k] * y[k].x;      zb += a[k] * y[k].y; }
      #pragma unroll
      for (int k = 0; k < 16; ++k) { za += bq[k] * y[16 + k].x; zb += bq[k] * y[16 + k].y; }
      #pragma unroll
      for (int k = 0; k < 4; ++k)  { za += cq[k] * y[32 + k].x; zb += cq[k] * y[32 + k].y; }
      vf2 zv; zv.x = za; zv.y = zb;
      *(vf2*)(z + (size_t)(l * R_DIM + r) * HW + p) = zv;
    }
  }
}

// ---------------------------------------------------------------------------
// K3: out[l,c,p] = x[l,c,p] + sum_r gW1[l,c,r] * z[l,r,p]
// float4 path: 4 px/thread, 1024 px/block -> 16 B/lane loads+stores (coalescing
// sweet spot), half the VMEM instruction count and half the waves of the old
// float2 version for the same 472 MB of traffic. gW1 rows via s_load -> SGPR
// FMA operands. Per-pixel accumulation order unchanged (r ascending, single
// accumulator, then x + a) -> bit-exact vs previous version.
// out stores nontemporal so the write stream doesn't evict x from L3
// (x = 236 MB < 256 MB Infinity Cache, warmed by K1).
// Grid: L * PBLK4 * 2 channel-halves = 904 blocks (tail block half-active).
// ---------------------------------------------------------------------------
__global__ __launch_bounds__(256) void bias_add_kernel(
    const float* __restrict__ x, const float* __restrict__ z,
    const float* __restrict__ wf, float* __restrict__ out) {
  const int b = blockIdx.x;
  const int half = b & 1;
  const int t = b >> 1;          // [0, 452)
  const int l = t / PBLK4;
  const int pb = t - l * PBLK4;
  const int p = pb * 1024 + threadIdx.x * 4;
  if (p >= HW) return;           // tail block (pb==112): upper half idle

  // ---- prologue: z[r] for 4 pixels (precomputed by zmap_kernel) ----
  vf4 zv[R_DIM];
  {
    const float* zp = z + (size_t)l * R_DIM * HW + p;
    #pragma unroll
    for (int r = 0; r < R_DIM; ++r) zv[r] = *(const vf4*)(zp + r * HW);
  }

  // ---- main loop: 64 channels, 8 at a time (gW1 rows via one s_load group) ----
  const float* w1base = wf + l * WF_DIM + half * (64 * R_DIM);
  const size_t xoff = (size_t)l * C_DIM * HW + (size_t)half * 64 * HW + (size_t)p;
  const float* xp = x + xoff;
  float* op = out + xoff;

  #pragma unroll 1
  for (int cc = 0; cc < 64; cc += 8) {
    vf16 w0, w1, w2, w3;  // 64 floats = gW1 rows for channels cc..cc+7
    const float* wp = w1base + cc * R_DIM;
    asm volatile(
        "s_load_dwordx16 %0, %4, 0x0\n\t"
        "s_load_dwordx16 %1, %4, 0x40\n\t"
        "s_load_dwordx16 %2, %4, 0x80\n\t"
        "s_load_dwordx16 %3, %4, 0xC0\n\t"
        "s_waitcnt lgkmcnt(0)"
        : "=&s"(w0), "=&s"(w1), "=&s"(w2), "=&s"(w3)
        : "s"(wp));
    float wl[64];
    #pragma unroll
    for (int k = 0; k < 16; ++k) {
      wl[k] = w0[k]; wl[16 + k] = w1[k]; wl[32 + k] = w2[k]; wl[48 + k] = w3[k];
    }
    #pragma unroll
    for (int c8 = 0; c8 < 8; ++c8) {
      float a0 = 0.f, a1 = 0.f, a2 = 0.f, a3 = 0.f;
      #pragma unroll
      for (int r = 0; r < R_DIM; ++r) {
        const float wv = wl[c8 * 8 + r];
        a0 += wv * zv[r].x;
        a1 += wv * zv[r].y;
        a2 += wv * zv[r].z;
        a3 += wv * zv[r].w;
      }
      const size_t co = (size_t)(cc + c8) * HW;
      vf4 xv = *(const vf4*)(xp + co);
      vf4 ov;
      ov.x = xv.x + a0;
      ov.y = xv.y + a1;
      ov.z = xv.z + a2;
      ov.w = xv.w + a3;
      __builtin_nontemporal_store(ov, (vf4*)(op + co));
    }
  }
}

// ---------------------------------------------------------------------------
extern "C" void kernel_launch(void* const* d_in, const int* in_sizes, int n_in,
                              void* d_out, int out_size, void* d_ws, size_t ws_size,
                              hipStream_t stream) {
  const float* x    = (const float*)d_in[0];
  const float* Wa   = (const float*)d_in[1];
  const float* ba   = (const float*)d_in[2];
  const float* Wb   = (const float*)d_in[3];
  const float* bb   = (const float*)d_in[4];
  const float* gain = (const float*)d_in[5];
  const float* Y    = (const float*)d_in[6];
  float* out = (float*)d_out;

  float* ctx = (float*)d_ws;                    // 512 floats
  float* wf  = (float*)((char*)d_ws + 4096);    // 5248 floats
  float* z   = (float*)((char*)d_ws + 32768);   // 4*8*115200 floats = 14.7 MB

  mean_pool_kernel<<<L_DIM * C_DIM, 256, 0, stream>>>(x, ctx);
  hyper_kernel<<<21, 256, 0, stream>>>(ctx, Wa, ba, Wb, bb, gain, wf);
  zmap_kernel<<<PBLK, 256, 0, stream>>>(Y, wf, z);
  bias_add_kernel<<<L_DIM * PBLK4 * 2, 256, 0, stream>>>(x, z, wf, out);
}